// Round 1
// 993.538 us; speedup vs baseline: 1.0898x; 1.0898x over previous
//
#include <hip/hip_runtime.h>

#define N_ 16384
#define E_ 262144
#define C_ 256
#define R_ 9
#define B_ 4
#define NKEY (N_ * R_)    // 147456
#define NKEY2 (2 * NKEY)  // 294912

typedef unsigned short u16;
typedef unsigned int u32;

typedef __bf16 bf16x8 __attribute__((ext_vector_type(8)));
typedef float f32x4 __attribute__((ext_vector_type(4)));
typedef unsigned short u16x8 __attribute__((ext_vector_type(8)));

__device__ __forceinline__ u16 f2bf(float x) {
  u32 u = __float_as_uint(x);
  u32 r = (u + 0x7fffu + ((u >> 16) & 1u)) >> 16;  // RNE
  return (u16)r;
}
__device__ __forceinline__ float bf2f(u16 h) {
  return __uint_as_float(((u32)h) << 16);
}

// async global->LDS, 16B per lane (guide §5: width=16 is the m97 lever)
__device__ __forceinline__ void gld16(const void* g, void* l) {
  __builtin_amdgcn_global_load_lds(
      (const __attribute__((address_space(1))) void*)g,
      (__attribute__((address_space(3))) void*)l, 16, 0, 0);
}

// ---------------------------------------------------------------------------
// merged prep: all four W^T matrices + both v vectors in one launch
// W1/W2 per-batch layout Bt[r][o][c]; W3/W4 stacked Bt[o][r*256+c]
// v[r][c] = sum_o W[r][c][o] * aw[r][o]
// ---------------------------------------------------------------------------
__global__ __launch_bounds__(256) void prep_kernel(
    const float* __restrict__ b1, const float* __restrict__ a1,
    const float* __restrict__ b2, const float* __restrict__ a2,
    const float* __restrict__ b3, const float* __restrict__ a3,
    const float* __restrict__ aw3,
    const float* __restrict__ b4, const float* __restrict__ a4,
    const float* __restrict__ aw4,
    u16* __restrict__ W1, u16* __restrict__ W2,
    u16* __restrict__ W3, u16* __restrict__ W4,
    float* __restrict__ v3, float* __restrict__ v4) {
  int c = blockIdx.x, r = blockIdx.y, o = threadIdx.x;
  float s1 = 0.f, s2 = 0.f, s3 = 0.f, s4 = 0.f;
#pragma unroll
  for (int b = 0; b < B_; ++b) {
    long bi = ((long)b * C_ + c) * C_ + o;
    s1 += a1[r * B_ + b] * b1[bi];
    s2 += a2[r * B_ + b] * b2[bi];
    s3 += a3[r * B_ + b] * b3[bi];
    s4 += a4[r * B_ + b] * b4[bi];
  }
  W1[((long)r * C_ + o) * C_ + c] = f2bf(s1);
  W2[((long)r * C_ + o) * C_ + c] = f2bf(s2);
  W3[(long)o * (R_ * C_) + r * C_ + c] = f2bf(s3);
  W4[(long)o * (R_ * C_) + r * C_ + c] = f2bf(s4);

  __shared__ float red[256];
  red[o] = s3 * aw3[r * C_ + o];
  __syncthreads();
  for (int s = 128; s > 0; s >>= 1) {
    if (o < s) red[o] += red[o + s];
    __syncthreads();
  }
  float rv3 = red[0];
  __syncthreads();
  red[o] = s4 * aw4[r * C_ + o];
  __syncthreads();
  for (int s = 128; s > 0; s >>= 1) {
    if (o < s) red[o] += red[o + s];
    __syncthreads();
  }
  if (o == 0) {
    v3[r * C_ + c] = rv3;
    v4[r * C_ + c] = red[0];
  }
}

__global__ void cvt_bf16_kernel(const float* __restrict__ in, u16* __restrict__ out) {
  long i = ((long)blockIdx.x * 256 + threadIdx.x) * 4;
  float4 f = *(const float4*)(in + i);
  ushort4 h;
  h.x = f2bf(f.x); h.y = f2bf(f.y); h.z = f2bf(f.z); h.w = f2bf(f.w);
  *(ushort4*)(out + i) = h;
}

// ---------------------------------------------------------------------------
// GEMM: Out[m][n] = sum_k A[m][k] * Bt[n][k]   (Bt N-major, bf16)
// 128x128x32 tile, 4 waves (2x2), global_load_lds(16B) staging, linear LDS.
// OMODE: 1 = bf16 out, 3 = node = nf + 0.5*dv[row]*acc, 4 = node += 0.5*dv*acc
// ---------------------------------------------------------------------------
#define BM 128
#define BN 128
#define BK 32

template <int OMODE>
__global__ __launch_bounds__(256) void gemm_kernel(
    const u16* __restrict__ A, long aBatch, int lda,
    const u16* __restrict__ Bt, long bBatch, int K,
    void* __restrict__ Out, long cBatch, int ldc,
    const float* __restrict__ nf, const float* __restrict__ dv) {
  __shared__ __attribute__((aligned(16))) u16 As[BM * BK];
  __shared__ __attribute__((aligned(16))) u16 Bs[BN * BK];

  const int t = threadIdx.x;
  const int m0 = blockIdx.x * BM;
  const int n0 = blockIdx.y * BN;
  const long zb = blockIdx.z;

  const int sr = t >> 2;          // staging row 0..63 (and +64)
  const int sk = (t & 3) * 8;     // k elem offset 0/8/16/24

  const int w = t >> 6, lane = t & 63;
  const int wm = (w >> 1) * 64, wn = (w & 1) * 64;
  const int lr = lane & 15;
  const int lk = (lane >> 4) * 8;

  f32x4 acc[4][4];
#pragma unroll
  for (int i = 0; i < 4; ++i)
#pragma unroll
    for (int j = 0; j < 4; ++j) acc[i][j] = (f32x4){0.f, 0.f, 0.f, 0.f};

  const u16* aR = A + zb * aBatch + (long)(m0 + sr) * lda + sk;
  const u16* bR = Bt + zb * bBatch + (long)(n0 + sr) * K + sk;
  const long aStep = 64L * lda;
  const long bStep = 64L * K;

  // linear LDS: dest elem offset == t*8 (wave-contiguous, required by gld_lds)
  u16* aD0 = &As[t * 8];
  u16* aD1 = &As[2048 + t * 8];
  u16* bD0 = &Bs[t * 8];
  u16* bD1 = &Bs[2048 + t * 8];

  for (int k0 = 0; k0 < K; k0 += BK) {
    gld16(aR, aD0);
    gld16(aR + aStep, aD1);
    gld16(bR, bD0);
    gld16(bR + bStep, bD1);
    aR += BK;
    bR += BK;
    __syncthreads();  // drains vmcnt -> LDS tile ready

    bf16x8 af[4], bg[4];
#pragma unroll
    for (int mi = 0; mi < 4; ++mi)
      af[mi] = *(const bf16x8*)&As[(wm + mi * 16 + lr) * BK + lk];
#pragma unroll
    for (int ni = 0; ni < 4; ++ni)
      bg[ni] = *(const bf16x8*)&Bs[(wn + ni * 16 + lr) * BK + lk];
#pragma unroll
    for (int mi = 0; mi < 4; ++mi)
#pragma unroll
      for (int ni = 0; ni < 4; ++ni)
        acc[mi][ni] = __builtin_amdgcn_mfma_f32_16x16x32_bf16(af[mi], bg[ni], acc[mi][ni], 0, 0, 0);

    __syncthreads();
  }

  long base = zb * cBatch;
#pragma unroll
  for (int mi = 0; mi < 4; ++mi) {
    int rowb = m0 + wm + mi * 16 + ((lane >> 4) * 4);
    float fs[4];
    if (OMODE >= 3) {
#pragma unroll
      for (int i = 0; i < 4; ++i) fs[i] = 0.5f * dv[rowb + i];
    }
#pragma unroll
    for (int ni = 0; ni < 4; ++ni) {
      int col = n0 + wn + ni * 16 + lr;
      f32x4 c = acc[mi][ni];
#pragma unroll
      for (int i = 0; i < 4; ++i) {
        long idx = base + (long)(rowb + i) * ldc + col;
        if (OMODE == 1) ((u16*)Out)[idx] = f2bf(c[i]);
        else if (OMODE == 3) ((float*)Out)[idx] = nf[idx] + fs[i] * c[i];
        else if (OMODE == 4) ((float*)Out)[idx] += fs[i] * c[i];
        else ((float*)Out)[idx] = c[i];
      }
    }
  }
}

// ---------------------------------------------------------------------------
// rel_emb + fused scores for both branches + merged key histogram
// 2 edges per wave: 32 lanes/edge, 8 channels/lane (16B gathers)
// ---------------------------------------------------------------------------
__global__ __launch_bounds__(256) void relemb_kernel(
    const float* __restrict__ ef, const u16* __restrict__ Ysub,
    const u16* __restrict__ Yobj, const int* __restrict__ src,
    const int* __restrict__ dst, const int* __restrict__ et,
    const int* __restrict__ eti, const float* __restrict__ vS,
    const float* __restrict__ abS, const float* __restrict__ vO,
    const float* __restrict__ abO, float* __restrict__ rel,
    float* __restrict__ scoreS, float* __restrict__ scoreO,
    int* __restrict__ cnt) {
  int e = blockIdx.x * 8 + (threadIdx.x >> 5);
  int h = threadIdx.x & 31;
  int c = h * 8;
  int sn = src[e], dn = dst[e], tf = et[e], ti = eti[e];

  u16x8 ys = *(const u16x8*)(Ysub + ((long)tf * N_ + sn) * C_ + c);
  u16x8 yo = *(const u16x8*)(Yobj + ((long)ti * N_ + dn) * C_ + c);
  long ei = (long)e * C_ + c;
  float4 f0 = *(const float4*)(ef + ei);
  float4 f1 = *(const float4*)(ef + ei + 4);

  float o0 = f0.x + 0.5f * (bf2f(ys[0]) + bf2f(yo[0]));
  float o1 = f0.y + 0.5f * (bf2f(ys[1]) + bf2f(yo[1]));
  float o2 = f0.z + 0.5f * (bf2f(ys[2]) + bf2f(yo[2]));
  float o3 = f0.w + 0.5f * (bf2f(ys[3]) + bf2f(yo[3]));
  float o4 = f1.x + 0.5f * (bf2f(ys[4]) + bf2f(yo[4]));
  float o5 = f1.y + 0.5f * (bf2f(ys[5]) + bf2f(yo[5]));
  float o6 = f1.z + 0.5f * (bf2f(ys[6]) + bf2f(yo[6]));
  float o7 = f1.w + 0.5f * (bf2f(ys[7]) + bf2f(yo[7]));
  *(float4*)(rel + ei) = (float4){o0, o1, o2, o3};
  *(float4*)(rel + ei + 4) = (float4){o4, o5, o6, o7};

  float4 wS0 = *(const float4*)(vS + ti * C_ + c);
  float4 wS1 = *(const float4*)(vS + ti * C_ + c + 4);
  float4 wO0 = *(const float4*)(vO + tf * C_ + c);
  float4 wO1 = *(const float4*)(vO + tf * C_ + c + 4);
  float pS = o0 * wS0.x + o1 * wS0.y + o2 * wS0.z + o3 * wS0.w +
             o4 * wS1.x + o5 * wS1.y + o6 * wS1.z + o7 * wS1.w;
  float pO = o0 * wO0.x + o1 * wO0.y + o2 * wO0.z + o3 * wO0.w +
             o4 * wO1.x + o5 * wO1.y + o6 * wO1.z + o7 * wO1.w;
#pragma unroll
  for (int off = 16; off > 0; off >>= 1) {
    pS += __shfl_xor(pS, off);
    pO += __shfl_xor(pO, off);
  }
  if (h == 0) {
    float sS = pS + abS[ti];
    sS = sS > 0.f ? sS : 0.01f * sS;
    scoreS[e] = sS;
    atomicAdd(&cnt[sn * R_ + ti], 1);
    float sO = pO + abO[tf];
    sO = sO > 0.f ? sO : 0.01f * sO;
    scoreO[e] = sO;
    atomicAdd(&cnt[NKEY + dn * R_ + tf], 1);
  }
}

// 1/div per node per branch (replaces per-element recompute in final)
__global__ __launch_bounds__(256) void div_kernel(const int* __restrict__ cnt,
                                                  float* __restrict__ divS,
                                                  float* __restrict__ divO) {
  int n = blockIdx.x * 256 + threadIdx.x;
  int ds = 0, dq = 0;
#pragma unroll
  for (int r = 0; r < R_; ++r) {
    ds += (cnt[n * R_ + r] > 0);
    dq += (cnt[NKEY + n * R_ + r] > 0);
  }
  divS[n] = ds ? 1.f / (float)ds : 1.f;
  divO[n] = dq ? 1.f / (float)dq : 1.f;
}

// ---------------------------------------------------------------------------
// merged hierarchical exclusive scan over NKEY2=294912 counts (288 x 1024)
// ---------------------------------------------------------------------------
__global__ __launch_bounds__(256) void scan1_kernel(const int* __restrict__ cnt,
                                                    int* __restrict__ offs,
                                                    int* __restrict__ part) {
  __shared__ int lds[256];
  int b = blockIdx.x, t = threadIdx.x;
  int base = b * 1024 + t * 4;
  int4 v = *(const int4*)(cnt + base);
  int tsum = v.x + v.y + v.z + v.w;
  lds[t] = tsum;
  __syncthreads();
  for (int d = 1; d < 256; d <<= 1) {
    int x = (t >= d) ? lds[t - d] : 0;
    __syncthreads();
    lds[t] += x;
    __syncthreads();
  }
  int run = (t == 0) ? 0 : lds[t - 1];
  int4 o;
  o.x = run;
  o.y = run + v.x;
  o.z = o.y + v.y;
  o.w = o.z + v.z;
  *(int4*)(offs + base) = o;
  if (t == 255) part[b] = lds[255];
}

__global__ __launch_bounds__(512) void scan2_kernel(int* __restrict__ part) {
  __shared__ int lds[512];
  int t = threadIdx.x;
  lds[t] = (t < 288) ? part[t] : 0;
  __syncthreads();
  for (int d = 1; d < 512; d <<= 1) {
    int x = (t >= d) ? lds[t - d] : 0;
    __syncthreads();
    lds[t] += x;
    __syncthreads();
  }
  if (t < 288) part[t] = (t == 0) ? 0 : lds[t - 1];
}

__global__ __launch_bounds__(256) void scan3_kernel(const int* __restrict__ part,
                                                    int* __restrict__ offs,
                                                    int* __restrict__ cursor) {
  int i = blockIdx.x * 256 + threadIdx.x;  // grid 1152
  int v = offs[i] + part[i >> 10];
  offs[i] = v;
  cursor[i] = v;
}

// one pass: scatter edge into both branches' key lists
__global__ __launch_bounds__(256) void scatter_kernel(
    const int* __restrict__ et, const int* __restrict__ eti,
    const int* __restrict__ src, const int* __restrict__ dst,
    int* __restrict__ cursor, int* __restrict__ order) {
  int e = blockIdx.x * 256 + threadIdx.x;
  int kS = src[e] * R_ + eti[e];
  int kO = NKEY + dst[e] * R_ + et[e];
  order[atomicAdd(&cursor[kS], 1)] = e;
  order[atomicAdd(&cursor[kO], 1)] = e;
}

// ---------------------------------------------------------------------------
// one wave per key (both branches in one launch): single-pass softmax
// (no max-subtraction: |score| <~ 14, exp is f32-safe; shift-invariant)
// ---------------------------------------------------------------------------
__global__ __launch_bounds__(256) void zgather_kernel(
    const float* __restrict__ rel, const float* __restrict__ scoreS,
    const float* __restrict__ scoreO, const int* __restrict__ order,
    const int* __restrict__ offs, const int* __restrict__ cnt,
    u16* __restrict__ zS, u16* __restrict__ zO) {
  int key = blockIdx.x * 4 + (threadIdx.x >> 6);
  int lane = threadIdx.x & 63;
  int c = lane * 4;
  int len = cnt[key];
  int start = offs[key];
  const float* score = scoreS;
  u16* z = zS;
  int k2 = key;
  if (key >= NKEY) { score = scoreO; z = zO; k2 = key - NKEY; }

  float ax = 0.f, ay = 0.f, az = 0.f, aw = 0.f, den = 0.f;
  for (int i = 0; i < len; ++i) {
    int e = order[start + i];
    float ex = __expf(score[e]);
    den += ex;
    float4 x = *(const float4*)(rel + (long)e * C_ + c);
    ax += ex * x.x; ay += ex * x.y; az += ex * x.z; aw += ex * x.w;
  }
  if (len > 0) {
    float inv = 1.f / den;
    ax *= inv; ay *= inv; az *= inv; aw *= inv;
  }
  int n = k2 / R_, r = k2 - n * R_;
  ushort4 h;
  h.x = f2bf(ax); h.y = f2bf(ay); h.z = f2bf(az); h.w = f2bf(aw);
  *(ushort4*)(z + (long)n * (R_ * C_) + r * C_ + c) = h;
}

// ---------------------------------------------------------------------------
extern "C" void kernel_launch(void* const* d_in, const int* in_sizes, int n_in,
                              void* d_out, int out_size, void* d_ws, size_t ws_size,
                              hipStream_t stream) {
  const int* edge_index = (const int*)d_in[0];
  const float* nf = (const float*)d_in[1];
  const float* ef = (const float*)d_in[2];
  const int* et = (const int*)d_in[3];
  const int* eti = (const int*)d_in[4];
  const float* s2r_basis = (const float*)d_in[6];
  const float* s2r_att = (const float*)d_in[7];
  const float* o2r_basis = (const float*)d_in[8];
  const float* o2r_att = (const float*)d_in[9];
  const float* r2s_basis = (const float*)d_in[10];
  const float* r2s_att = (const float*)d_in[11];
  const float* r2s_aw = (const float*)d_in[12];
  const float* r2s_ab = (const float*)d_in[13];
  const float* r2o_basis = (const float*)d_in[14];
  const float* r2o_att = (const float*)d_in[15];
  const float* r2o_aw = (const float*)d_in[16];
  const float* r2o_ab = (const float*)d_in[17];

  const int* src = edge_index;
  const int* dst = edge_index + E_;

  char* ws = (char*)d_ws;
  u16* WtSub = (u16*)(ws + 0);             // 1179648
  u16* WtObj = (u16*)(ws + 1179648);
  u16* WtR2S = (u16*)(ws + 2359296);
  u16* WtR2O = (u16*)(ws + 3538944);
  float* vS = (float*)(ws + 4718592);      // 9216
  float* vO = (float*)(ws + 4727808);
  u16* nfb = (u16*)(ws + 4737024);         // 8 MB -> 13125632
  float* scoreS = (float*)(ws + 13125632);
  float* scoreO = (float*)(ws + 14174208);
  int* cnt = (int*)(ws + 15222784);        // 2*NKEY ints -> 16402432
  int* offs = (int*)(ws + 16402432);       // -> 17582080
  int* cursor = (int*)(ws + 17582080);     // -> 18761728
  int* order = (int*)(ws + 18761728);      // 2E ints -> 20858880
  int* part = (int*)(ws + 20858880);       // -> 20860928
  float* divS = (float*)(ws + 20860928);   // -> 20926464
  float* divO = (float*)(ws + 20926464);   // -> 20992000
  u16* Ysub = (u16*)(ws + 20992000);       // 75.5 MB -> 96489472
  u16* Yobj = (u16*)(ws + 96489472);       // 75.5 MB -> 171986944
  u16* zS = Ysub;  // dead after relemb
  u16* zO = Yobj;  // dead after relemb

  float* node_out = (float*)d_out;
  float* rel_out = (float*)d_out + (long)N_ * C_;

  // ---- prep (one launch) ----
  prep_kernel<<<dim3(C_, R_), 256, 0, stream>>>(
      s2r_basis, s2r_att, o2r_basis, o2r_att,
      r2s_basis, r2s_att, r2s_aw, r2o_basis, r2o_att, r2o_aw,
      WtSub, WtObj, WtR2S, WtR2O, vS, vO);
  cvt_bf16_kernel<<<(N_ * C_) / 1024, 256, 0, stream>>>(nf, nfb);
  hipMemsetAsync(cnt, 0, (size_t)NKEY2 * 4, stream);

  // ---- Y[r] = nf @ W_r (batched over r), bf16 out ----
  gemm_kernel<1><<<dim3(N_ / BM, C_ / BN, R_), 256, 0, stream>>>(
      nfb, 0L, C_, WtSub, (long)C_ * C_, C_, Ysub, (long)N_ * C_, C_, nullptr, nullptr);
  gemm_kernel<1><<<dim3(N_ / BM, C_ / BN, R_), 256, 0, stream>>>(
      nfb, 0L, C_, WtObj, (long)C_ * C_, C_, Yobj, (long)N_ * C_, C_, nullptr, nullptr);

  // ---- rel_emb + scores + merged histogram ----
  relemb_kernel<<<E_ / 8, 256, 0, stream>>>(ef, Ysub, Yobj, src, dst, et, eti,
                                            vS, r2s_ab, vO, r2o_ab, rel_out,
                                            scoreS, scoreO, cnt);
  div_kernel<<<N_ / 256, 256, 0, stream>>>(cnt, divS, divO);

  // ---- merged scan + scatter + zgather (both branches) ----
  scan1_kernel<<<288, 256, 0, stream>>>(cnt, offs, part);
  scan2_kernel<<<1, 512, 0, stream>>>(part);
  scan3_kernel<<<NKEY2 / 256, 256, 0, stream>>>(part, offs, cursor);
  scatter_kernel<<<E_ / 256, 256, 0, stream>>>(et, eti, src, dst, cursor, order);
  zgather_kernel<<<NKEY2 / 4, 256, 0, stream>>>(rel_out, scoreS, scoreO, order,
                                                offs, cnt, zS, zO);

  // ---- agg GEMMs with fused final epilogue ----
  gemm_kernel<3><<<dim3(N_ / BM, C_ / BN, 1), 256, 0, stream>>>(
      zS, 0L, R_ * C_, WtR2S, 0L, R_ * C_, node_out, 0L, C_, nf, divS);
  gemm_kernel<4><<<dim3(N_ / BM, C_ / BN, 1), 256, 0, stream>>>(
      zO, 0L, R_ * C_, WtR2O, 0L, R_ * C_, node_out, 0L, C_, nullptr, divO);

  (void)in_sizes; (void)n_in; (void)out_size; (void)ws_size;
}

// Round 2
// 930.050 us; speedup vs baseline: 1.1642x; 1.0683x over previous
//
#include <hip/hip_runtime.h>

#define N_ 16384
#define E_ 262144
#define C_ 256
#define R_ 9
#define B_ 4
#define NKEY (N_ * R_)    // 147456
#define NKEY2 (2 * NKEY)  // 294912

typedef unsigned short u16;
typedef unsigned int u32;

typedef __bf16 bf16x8 __attribute__((ext_vector_type(8)));
typedef float f32x4 __attribute__((ext_vector_type(4)));
typedef unsigned short u16x8 __attribute__((ext_vector_type(8)));

__device__ __forceinline__ u16 f2bf(float x) {
  u32 u = __float_as_uint(x);
  u32 r = (u + 0x7fffu + ((u >> 16) & 1u)) >> 16;  // RNE
  return (u16)r;
}
__device__ __forceinline__ float bf2f(u16 h) {
  return __uint_as_float(((u32)h) << 16);
}

// async global->LDS, 16B per lane (guide §5: width=16 is the m97 lever)
__device__ __forceinline__ void gld16(const void* g, void* l) {
  __builtin_amdgcn_global_load_lds(
      (const __attribute__((address_space(1))) void*)g,
      (__attribute__((address_space(3))) void*)l, 16, 0, 0);
}

// ---------------------------------------------------------------------------
// merged prep: all four W^T matrices + both v vectors in one launch
// ---------------------------------------------------------------------------
__global__ __launch_bounds__(256) void prep_kernel(
    const float* __restrict__ b1, const float* __restrict__ a1,
    const float* __restrict__ b2, const float* __restrict__ a2,
    const float* __restrict__ b3, const float* __restrict__ a3,
    const float* __restrict__ aw3,
    const float* __restrict__ b4, const float* __restrict__ a4,
    const float* __restrict__ aw4,
    u16* __restrict__ W1, u16* __restrict__ W2,
    u16* __restrict__ W3, u16* __restrict__ W4,
    float* __restrict__ v3, float* __restrict__ v4) {
  int c = blockIdx.x, r = blockIdx.y, o = threadIdx.x;
  float s1 = 0.f, s2 = 0.f, s3 = 0.f, s4 = 0.f;
#pragma unroll
  for (int b = 0; b < B_; ++b) {
    long bi = ((long)b * C_ + c) * C_ + o;
    s1 += a1[r * B_ + b] * b1[bi];
    s2 += a2[r * B_ + b] * b2[bi];
    s3 += a3[r * B_ + b] * b3[bi];
    s4 += a4[r * B_ + b] * b4[bi];
  }
  W1[((long)r * C_ + o) * C_ + c] = f2bf(s1);
  W2[((long)r * C_ + o) * C_ + c] = f2bf(s2);
  W3[(long)o * (R_ * C_) + r * C_ + c] = f2bf(s3);
  W4[(long)o * (R_ * C_) + r * C_ + c] = f2bf(s4);

  __shared__ float red[256];
  red[o] = s3 * aw3[r * C_ + o];
  __syncthreads();
  for (int s = 128; s > 0; s >>= 1) {
    if (o < s) red[o] += red[o + s];
    __syncthreads();
  }
  float rv3 = red[0];
  __syncthreads();
  red[o] = s4 * aw4[r * C_ + o];
  __syncthreads();
  for (int s = 128; s > 0; s >>= 1) {
    if (o < s) red[o] += red[o + s];
    __syncthreads();
  }
  if (o == 0) {
    v3[r * C_ + c] = rv3;
    v4[r * C_ + c] = red[0];
  }
}

__global__ void cvt_bf16_kernel(const float* __restrict__ in, u16* __restrict__ out) {
  long i = ((long)blockIdx.x * 256 + threadIdx.x) * 4;
  float4 f = *(const float4*)(in + i);
  ushort4 h;
  h.x = f2bf(f.x); h.y = f2bf(f.y); h.z = f2bf(f.z); h.w = f2bf(f.w);
  *(ushort4*)(out + i) = h;
}

// ---------------------------------------------------------------------------
// GEMM 128x128x32: Out[m][n] = sum_k A[m][k] * Bt[n][k]
// ---------------------------------------------------------------------------
#define BM 128
#define BN 128
#define BK 32

template <int OMODE>
__global__ __launch_bounds__(256) void gemm_kernel(
    const u16* __restrict__ A, long aBatch, int lda,
    const u16* __restrict__ Bt, long bBatch, int K,
    void* __restrict__ Out, long cBatch, int ldc) {
  __shared__ __attribute__((aligned(16))) u16 As[BM * BK];
  __shared__ __attribute__((aligned(16))) u16 Bs[BN * BK];

  const int t = threadIdx.x;
  const int m0 = blockIdx.x * BM;
  const int n0 = blockIdx.y * BN;
  const long zb = blockIdx.z;

  const int sr = t >> 2;
  const int sk = (t & 3) * 8;

  const int w = t >> 6, lane = t & 63;
  const int wm = (w >> 1) * 64, wn = (w & 1) * 64;
  const int lr = lane & 15;
  const int lk = (lane >> 4) * 8;

  f32x4 acc[4][4];
#pragma unroll
  for (int i = 0; i < 4; ++i)
#pragma unroll
    for (int j = 0; j < 4; ++j) acc[i][j] = (f32x4){0.f, 0.f, 0.f, 0.f};

  const u16* aR = A + zb * aBatch + (long)(m0 + sr) * lda + sk;
  const u16* bR = Bt + zb * bBatch + (long)(n0 + sr) * K + sk;
  const long aStep = 64L * lda;
  const long bStep = 64L * K;

  u16* aD0 = &As[t * 8];
  u16* aD1 = &As[2048 + t * 8];
  u16* bD0 = &Bs[t * 8];
  u16* bD1 = &Bs[2048 + t * 8];

  for (int k0 = 0; k0 < K; k0 += BK) {
    gld16(aR, aD0);
    gld16(aR + aStep, aD1);
    gld16(bR, bD0);
    gld16(bR + bStep, bD1);
    aR += BK;
    bR += BK;
    __syncthreads();

    bf16x8 af[4], bg[4];
#pragma unroll
    for (int mi = 0; mi < 4; ++mi)
      af[mi] = *(const bf16x8*)&As[(wm + mi * 16 + lr) * BK + lk];
#pragma unroll
    for (int ni = 0; ni < 4; ++ni)
      bg[ni] = *(const bf16x8*)&Bs[(wn + ni * 16 + lr) * BK + lk];
#pragma unroll
    for (int mi = 0; mi < 4; ++mi)
#pragma unroll
      for (int ni = 0; ni < 4; ++ni)
        acc[mi][ni] = __builtin_amdgcn_mfma_f32_16x16x32_bf16(af[mi], bg[ni], acc[mi][ni], 0, 0, 0);

    __syncthreads();
  }

  long base = zb * cBatch;
#pragma unroll
  for (int mi = 0; mi < 4; ++mi) {
    int rowb = m0 + wm + mi * 16 + ((lane >> 4) * 4);
#pragma unroll
    for (int ni = 0; ni < 4; ++ni) {
      int col = n0 + wn + ni * 16 + lr;
      f32x4 c = acc[mi][ni];
#pragma unroll
      for (int i = 0; i < 4; ++i) {
        long idx = base + (long)(rowb + i) * ldc + col;
        if (OMODE == 1) ((u16*)Out)[idx] = f2bf(c[i]);
        else ((float*)Out)[idx] = c[i];
      }
    }
  }
}

// ---------------------------------------------------------------------------
// GEMM 64x128x32 for the skinny K=2304 agg GEMMs: grid 512 = 2 blocks/CU
// OMODE: 3 = node = nf + 0.5*dv[row]*acc, 4 = node += 0.5*dv[row]*acc
// ---------------------------------------------------------------------------
template <int OMODE>
__global__ __launch_bounds__(256) void gemm64_kernel(
    const u16* __restrict__ A, int lda,
    const u16* __restrict__ Bt, int K,
    float* __restrict__ Out, int ldc,
    const float* __restrict__ nf, const float* __restrict__ dv) {
  __shared__ __attribute__((aligned(16))) u16 As[64 * BK];
  __shared__ __attribute__((aligned(16))) u16 Bs[BN * BK];

  const int t = threadIdx.x;
  const int m0 = blockIdx.x * 64;
  const int n0 = blockIdx.y * BN;

  const int sr = t >> 2;
  const int sk = (t & 3) * 8;

  const int w = t >> 6, lane = t & 63;
  const int wm = (w >> 1) * 32, wn = (w & 1) * 64;
  const int lr = lane & 15;
  const int lk = (lane >> 4) * 8;

  f32x4 acc[2][4];
#pragma unroll
  for (int i = 0; i < 2; ++i)
#pragma unroll
    for (int j = 0; j < 4; ++j) acc[i][j] = (f32x4){0.f, 0.f, 0.f, 0.f};

  const u16* aR = A + (long)(m0 + sr) * lda + sk;
  const u16* bR = Bt + (long)(n0 + sr) * K + sk;
  const long bStep = 64L * K;

  u16* aD = &As[t * 8];
  u16* bD0 = &Bs[t * 8];
  u16* bD1 = &Bs[2048 + t * 8];

  for (int k0 = 0; k0 < K; k0 += BK) {
    gld16(aR, aD);
    gld16(bR, bD0);
    gld16(bR + bStep, bD1);
    aR += BK;
    bR += BK;
    __syncthreads();

    bf16x8 af[2], bg[4];
#pragma unroll
    for (int mi = 0; mi < 2; ++mi)
      af[mi] = *(const bf16x8*)&As[(wm + mi * 16 + lr) * BK + lk];
#pragma unroll
    for (int ni = 0; ni < 4; ++ni)
      bg[ni] = *(const bf16x8*)&Bs[(wn + ni * 16 + lr) * BK + lk];
#pragma unroll
    for (int mi = 0; mi < 2; ++mi)
#pragma unroll
      for (int ni = 0; ni < 4; ++ni)
        acc[mi][ni] = __builtin_amdgcn_mfma_f32_16x16x32_bf16(af[mi], bg[ni], acc[mi][ni], 0, 0, 0);

    __syncthreads();
  }

#pragma unroll
  for (int mi = 0; mi < 2; ++mi) {
    int rowb = m0 + wm + mi * 16 + ((lane >> 4) * 4);
    float fs[4];
#pragma unroll
    for (int i = 0; i < 4; ++i) fs[i] = 0.5f * dv[rowb + i];
#pragma unroll
    for (int ni = 0; ni < 4; ++ni) {
      int col = n0 + wn + ni * 16 + lr;
      f32x4 c = acc[mi][ni];
#pragma unroll
      for (int i = 0; i < 4; ++i) {
        long idx = (long)(rowb + i) * ldc + col;
        if (OMODE == 3) Out[idx] = nf[idx] + fs[i] * c[i];
        else Out[idx] += fs[i] * c[i];
      }
    }
  }
}

// ---------------------------------------------------------------------------
// rel_emb + fused scores for both branches + merged key histogram
// 2 edges per wave: 32 lanes/edge, 8 channels/lane (16B gathers)
// ---------------------------------------------------------------------------
__global__ __launch_bounds__(256) void relemb_kernel(
    const float* __restrict__ ef, const u16* __restrict__ Ysub,
    const u16* __restrict__ Yobj, const int* __restrict__ src,
    const int* __restrict__ dst, const int* __restrict__ et,
    const int* __restrict__ eti, const float* __restrict__ vS,
    const float* __restrict__ abS, const float* __restrict__ vO,
    const float* __restrict__ abO, float* __restrict__ rel,
    float* __restrict__ scoreS, float* __restrict__ scoreO,
    int* __restrict__ cnt) {
  int e = blockIdx.x * 8 + (threadIdx.x >> 5);
  int h = threadIdx.x & 31;
  int c = h * 8;
  int sn = src[e], dn = dst[e], tf = et[e], ti = eti[e];

  u16x8 ys = *(const u16x8*)(Ysub + ((long)tf * N_ + sn) * C_ + c);
  u16x8 yo = *(const u16x8*)(Yobj + ((long)ti * N_ + dn) * C_ + c);
  long ei = (long)e * C_ + c;
  float4 f0 = *(const float4*)(ef + ei);
  float4 f1 = *(const float4*)(ef + ei + 4);

  float o0 = f0.x + 0.5f * (bf2f(ys[0]) + bf2f(yo[0]));
  float o1 = f0.y + 0.5f * (bf2f(ys[1]) + bf2f(yo[1]));
  float o2 = f0.z + 0.5f * (bf2f(ys[2]) + bf2f(yo[2]));
  float o3 = f0.w + 0.5f * (bf2f(ys[3]) + bf2f(yo[3]));
  float o4 = f1.x + 0.5f * (bf2f(ys[4]) + bf2f(yo[4]));
  float o5 = f1.y + 0.5f * (bf2f(ys[5]) + bf2f(yo[5]));
  float o6 = f1.z + 0.5f * (bf2f(ys[6]) + bf2f(yo[6]));
  float o7 = f1.w + 0.5f * (bf2f(ys[7]) + bf2f(yo[7]));
  *(float4*)(rel + ei) = (float4){o0, o1, o2, o3};
  *(float4*)(rel + ei + 4) = (float4){o4, o5, o6, o7};

  float4 wS0 = *(const float4*)(vS + ti * C_ + c);
  float4 wS1 = *(const float4*)(vS + ti * C_ + c + 4);
  float4 wO0 = *(const float4*)(vO + tf * C_ + c);
  float4 wO1 = *(const float4*)(vO + tf * C_ + c + 4);
  float pS = o0 * wS0.x + o1 * wS0.y + o2 * wS0.z + o3 * wS0.w +
             o4 * wS1.x + o5 * wS1.y + o6 * wS1.z + o7 * wS1.w;
  float pO = o0 * wO0.x + o1 * wO0.y + o2 * wO0.z + o3 * wO0.w +
             o4 * wO1.x + o5 * wO1.y + o6 * wO1.z + o7 * wO1.w;
#pragma unroll
  for (int off = 16; off > 0; off >>= 1) {
    pS += __shfl_xor(pS, off);
    pO += __shfl_xor(pO, off);
  }
  if (h == 0) {
    float sS = pS + abS[ti];
    sS = sS > 0.f ? sS : 0.01f * sS;
    scoreS[e] = sS;
    atomicAdd(&cnt[sn * R_ + ti], 1);
    float sO = pO + abO[tf];
    sO = sO > 0.f ? sO : 0.01f * sO;
    scoreO[e] = sO;
    atomicAdd(&cnt[NKEY + dn * R_ + tf], 1);
  }
}

__global__ __launch_bounds__(256) void div_kernel(const int* __restrict__ cnt,
                                                  float* __restrict__ divS,
                                                  float* __restrict__ divO) {
  int n = blockIdx.x * 256 + threadIdx.x;
  int ds = 0, dq = 0;
#pragma unroll
  for (int r = 0; r < R_; ++r) {
    ds += (cnt[n * R_ + r] > 0);
    dq += (cnt[NKEY + n * R_ + r] > 0);
  }
  divS[n] = ds ? 1.f / (float)ds : 1.f;
  divO[n] = dq ? 1.f / (float)dq : 1.f;
}

// ---------------------------------------------------------------------------
// merged hierarchical exclusive scan over NKEY2=294912 counts (288 x 1024)
// ---------------------------------------------------------------------------
__global__ __launch_bounds__(256) void scan1_kernel(const int* __restrict__ cnt,
                                                    int* __restrict__ offs,
                                                    int* __restrict__ part) {
  __shared__ int lds[256];
  int b = blockIdx.x, t = threadIdx.x;
  int base = b * 1024 + t * 4;
  int4 v = *(const int4*)(cnt + base);
  int tsum = v.x + v.y + v.z + v.w;
  lds[t] = tsum;
  __syncthreads();
  for (int d = 1; d < 256; d <<= 1) {
    int x = (t >= d) ? lds[t - d] : 0;
    __syncthreads();
    lds[t] += x;
    __syncthreads();
  }
  int run = (t == 0) ? 0 : lds[t - 1];
  int4 o;
  o.x = run;
  o.y = run + v.x;
  o.z = o.y + v.y;
  o.w = o.z + v.z;
  *(int4*)(offs + base) = o;
  if (t == 255) part[b] = lds[255];
}

__global__ __launch_bounds__(512) void scan2_kernel(int* __restrict__ part) {
  __shared__ int lds[512];
  int t = threadIdx.x;
  lds[t] = (t < 288) ? part[t] : 0;
  __syncthreads();
  for (int d = 1; d < 512; d <<= 1) {
    int x = (t >= d) ? lds[t - d] : 0;
    __syncthreads();
    lds[t] += x;
    __syncthreads();
  }
  if (t < 288) part[t] = (t == 0) ? 0 : lds[t - 1];
}

__global__ __launch_bounds__(256) void scan3_kernel(const int* __restrict__ part,
                                                    int* __restrict__ offs,
                                                    int* __restrict__ cursor) {
  int i = blockIdx.x * 256 + threadIdx.x;  // grid 1152
  int v = offs[i] + part[i >> 10];
  offs[i] = v;
  cursor[i] = v;
}

// one pass: scatter edge into both branches' key lists
__global__ __launch_bounds__(256) void scatter_kernel(
    const int* __restrict__ et, const int* __restrict__ eti,
    const int* __restrict__ src, const int* __restrict__ dst,
    int* __restrict__ cursor, int* __restrict__ order) {
  int e = blockIdx.x * 256 + threadIdx.x;
  int kS = src[e] * R_ + eti[e];
  int kO = NKEY + dst[e] * R_ + et[e];
  order[atomicAdd(&cursor[kS], 1)] = e;
  order[atomicAdd(&cursor[kO], 1)] = e;
}

// ---------------------------------------------------------------------------
// one wave per key, both branches in one launch.
// latency fix: parallel preload of edge list + exp(score) across lanes,
// shfl-broadcast in the weighted-sum loop -> independent rel row loads.
// len==1: softmax == 1 exactly -> straight row copy (no score load).
// ---------------------------------------------------------------------------
__global__ __launch_bounds__(256) void zgather_kernel(
    const float* __restrict__ rel, const float* __restrict__ scoreS,
    const float* __restrict__ scoreO, const int* __restrict__ order,
    const int* __restrict__ offs, const int* __restrict__ cnt,
    u16* __restrict__ zS, u16* __restrict__ zO) {
  int key = blockIdx.x * 4 + (threadIdx.x >> 6);
  int lane = threadIdx.x & 63;
  int c = lane * 4;
  int len = cnt[key];
  int start = offs[key];
  const float* score = scoreS;
  u16* z = zS;
  int k2 = key;
  if (key >= NKEY) { score = scoreO; z = zO; k2 = key - NKEY; }

  float ax = 0.f, ay = 0.f, az = 0.f, aw = 0.f;
  if (len == 1) {
    int e = order[start];
    float4 x = *(const float4*)(rel + (long)e * C_ + c);
    ax = x.x; ay = x.y; az = x.z; aw = x.w;
  } else if (len > 1 && len <= 64) {
    int e_l = 0;
    float s_l = 0.f;
    if (lane < len) {
      e_l = order[start + lane];
      s_l = __expf(score[e_l]);
    }
    float den = s_l;
#pragma unroll
    for (int off = 32; off > 0; off >>= 1) den += __shfl_xor(den, off);
    float inv = 1.f / den;
    int i = 0;
    for (; i + 2 <= len; i += 2) {
      int e0 = __shfl(e_l, i);
      int e1 = __shfl(e_l, i + 1);
      float a0 = __shfl(s_l, i) * inv;
      float a1 = __shfl(s_l, i + 1) * inv;
      float4 x0 = *(const float4*)(rel + (long)e0 * C_ + c);
      float4 x1 = *(const float4*)(rel + (long)e1 * C_ + c);
      ax += a0 * x0.x + a1 * x1.x;
      ay += a0 * x0.y + a1 * x1.y;
      az += a0 * x0.z + a1 * x1.z;
      aw += a0 * x0.w + a1 * x1.w;
    }
    if (i < len) {
      int e0 = __shfl(e_l, i);
      float a0 = __shfl(s_l, i) * inv;
      float4 x0 = *(const float4*)(rel + (long)e0 * C_ + c);
      ax += a0 * x0.x;
      ay += a0 * x0.y;
      az += a0 * x0.z;
      aw += a0 * x0.w;
    }
  } else if (len > 64) {
    float den = 0.f;
    for (int i = 0; i < len; ++i) {
      int e = order[start + i];
      float ex = __expf(score[e]);
      den += ex;
      float4 x = *(const float4*)(rel + (long)e * C_ + c);
      ax += ex * x.x; ay += ex * x.y; az += ex * x.z; aw += ex * x.w;
    }
    float inv = 1.f / den;
    ax *= inv; ay *= inv; az *= inv; aw *= inv;
  }
  int n = k2 / R_, r = k2 - n * R_;
  ushort4 h;
  h.x = f2bf(ax); h.y = f2bf(ay); h.z = f2bf(az); h.w = f2bf(aw);
  *(ushort4*)(z + (long)n * (R_ * C_) + r * C_ + c) = h;
}

// ---------------------------------------------------------------------------
extern "C" void kernel_launch(void* const* d_in, const int* in_sizes, int n_in,
                              void* d_out, int out_size, void* d_ws, size_t ws_size,
                              hipStream_t stream) {
  const int* edge_index = (const int*)d_in[0];
  const float* nf = (const float*)d_in[1];
  const float* ef = (const float*)d_in[2];
  const int* et = (const int*)d_in[3];
  const int* eti = (const int*)d_in[4];
  const float* s2r_basis = (const float*)d_in[6];
  const float* s2r_att = (const float*)d_in[7];
  const float* o2r_basis = (const float*)d_in[8];
  const float* o2r_att = (const float*)d_in[9];
  const float* r2s_basis = (const float*)d_in[10];
  const float* r2s_att = (const float*)d_in[11];
  const float* r2s_aw = (const float*)d_in[12];
  const float* r2s_ab = (const float*)d_in[13];
  const float* r2o_basis = (const float*)d_in[14];
  const float* r2o_att = (const float*)d_in[15];
  const float* r2o_aw = (const float*)d_in[16];
  const float* r2o_ab = (const float*)d_in[17];

  const int* src = edge_index;
  const int* dst = edge_index + E_;

  char* ws = (char*)d_ws;
  u16* WtSub = (u16*)(ws + 0);             // 1179648
  u16* WtObj = (u16*)(ws + 1179648);
  u16* WtR2S = (u16*)(ws + 2359296);
  u16* WtR2O = (u16*)(ws + 3538944);
  float* vS = (float*)(ws + 4718592);      // 9216
  float* vO = (float*)(ws + 4727808);
  u16* nfb = (u16*)(ws + 4737024);         // 8 MB -> 13125632
  float* scoreS = (float*)(ws + 13125632);
  float* scoreO = (float*)(ws + 14174208);
  int* cnt = (int*)(ws + 15222784);        // 2*NKEY ints -> 16402432
  int* offs = (int*)(ws + 16402432);       // -> 17582080
  int* cursor = (int*)(ws + 17582080);     // -> 18761728
  int* order = (int*)(ws + 18761728);      // 2E ints -> 20858880
  int* part = (int*)(ws + 20858880);       // -> 20860928
  float* divS = (float*)(ws + 20860928);   // -> 20926464
  float* divO = (float*)(ws + 20926464);   // -> 20992000
  u16* Ysub = (u16*)(ws + 20992000);       // 75.5 MB -> 96489472
  u16* Yobj = (u16*)(ws + 96489472);       // 75.5 MB -> 171986944
  u16* zS = Ysub;  // dead after relemb
  u16* zO = Yobj;  // dead after relemb

  float* node_out = (float*)d_out;
  float* rel_out = (float*)d_out + (long)N_ * C_;

  // ---- prep (one launch) ----
  prep_kernel<<<dim3(C_, R_), 256, 0, stream>>>(
      s2r_basis, s2r_att, o2r_basis, o2r_att,
      r2s_basis, r2s_att, r2s_aw, r2o_basis, r2o_att, r2o_aw,
      WtSub, WtObj, WtR2S, WtR2O, vS, vO);
  cvt_bf16_kernel<<<(N_ * C_) / 1024, 256, 0, stream>>>(nf, nfb);
  hipMemsetAsync(cnt, 0, (size_t)NKEY2 * 4, stream);

  // ---- Y[r] = nf @ W_r (batched over r), bf16 out ----
  gemm_kernel<1><<<dim3(N_ / BM, C_ / BN, R_), 256, 0, stream>>>(
      nfb, 0L, C_, WtSub, (long)C_ * C_, C_, Ysub, (long)N_ * C_, C_);
  gemm_kernel<1><<<dim3(N_ / BM, C_ / BN, R_), 256, 0, stream>>>(
      nfb, 0L, C_, WtObj, (long)C_ * C_, C_, Yobj, (long)N_ * C_, C_);

  // ---- rel_emb + scores + merged histogram ----
  relemb_kernel<<<E_ / 8, 256, 0, stream>>>(ef, Ysub, Yobj, src, dst, et, eti,
                                            vS, r2s_ab, vO, r2o_ab, rel_out,
                                            scoreS, scoreO, cnt);
  div_kernel<<<N_ / 256, 256, 0, stream>>>(cnt, divS, divO);

  // ---- merged scan + scatter + zgather (both branches) ----
  scan1_kernel<<<288, 256, 0, stream>>>(cnt, offs, part);
  scan2_kernel<<<1, 512, 0, stream>>>(part);
  scan3_kernel<<<NKEY2 / 256, 256, 0, stream>>>(part, offs, cursor);
  scatter_kernel<<<E_ / 256, 256, 0, stream>>>(et, eti, src, dst, cursor, order);
  zgather_kernel<<<NKEY2 / 4, 256, 0, stream>>>(rel_out, scoreS, scoreO, order,
                                                offs, cnt, zS, zO);

  // ---- agg GEMMs (BM=64 -> 512 blocks, 2/CU) with fused final epilogue ----
  gemm64_kernel<3><<<dim3(N_ / 64, C_ / BN), 256, 0, stream>>>(
      zS, R_ * C_, WtR2S, R_ * C_, node_out, C_, nf, divS);
  gemm64_kernel<4><<<dim3(N_ / 64, C_ / BN), 256, 0, stream>>>(
      zO, R_ * C_, WtR2O, R_ * C_, node_out, C_, nullptr, divO);

  (void)in_sizes; (void)n_in; (void)out_size; (void)ws_size;
}